// Round 1
// baseline (896.683 us; speedup 1.0000x reference)
//
#include <hip/hip_runtime.h>

#define NEG_INF -1e30f

typedef __attribute__((ext_vector_type(8))) __bf16 bf16x8;
typedef __attribute__((ext_vector_type(4))) float f32x4;

constexpr int Bb = 16, T = 800, D = 512, V = 5000, L = 100;
constexpr int ROWS = Bb * T;        // 12800
constexpr int S = 2 * L + 1;        // 201
constexpr int SP = 208;             // padded S (13*16)
constexpr int NCB = (V + 63) / 64;  // 79 col-blocks
constexpr int NRB = ROWS / 64;      // 200 row-blocks

// float -> bf16 bits, round-to-nearest-even
static __device__ __forceinline__ unsigned short f2bf(float x) {
  union { float f; unsigned u; } v; v.f = x;
  unsigned r = (v.u + 0x7FFFu + ((v.u >> 16) & 1u)) >> 16;
  return (unsigned short)r;
}

// ---- hs fp32 -> bf16 (row-major [12800][512]) ----
__global__ __launch_bounds__(256) void k_conv_hs(const float* __restrict__ hs,
                                                 unsigned short* __restrict__ A) {
  int i = blockIdx.x * 256 + threadIdx.x;  // group of 4 elements
  float4 f = ((const float4*)hs)[i];
  ushort4 o;
  o.x = f2bf(f.x); o.y = f2bf(f.y); o.z = f2bf(f.z); o.w = f2bf(f.w);
  ((ushort4*)A)[i] = o;
}

// ---- W [512][5000] fp32 -> Wt [5056][512] bf16 (transposed, pad rows zero) ----
__global__ __launch_bounds__(256) void k_transW(const float* __restrict__ W,
                                                unsigned short* __restrict__ Wt) {
  __shared__ float tile[64][65];
  int v0 = blockIdx.x * 64, k0 = blockIdx.y * 64;
  int tl = threadIdx.x & 63, th = threadIdx.x >> 6;
#pragma unroll
  for (int i = 0; i < 16; i++) {
    int k = k0 + th + i * 4;
    int v = v0 + tl;
    tile[th + i * 4][tl] = (v < V) ? W[(size_t)k * V + v] : 0.f;
  }
  __syncthreads();
#pragma unroll
  for (int i = 0; i < 16; i++) {
    int v = v0 + th + i * 4;
    int k = k0 + tl;
    Wt[(size_t)v * D + k] = f2bf(tile[tl][th + i * 4]);
  }
}

// ---- fused GEMM + per-row online softmax partials over 64-col tile ----
// grid (79 colblocks, 200 rowblocks), 256 thr (4 waves). Wave w: rows w*16..+15.
__global__ __launch_bounds__(256) void k_gemm_lse(const unsigned short* __restrict__ A,
                                                  const unsigned short* __restrict__ Wt,
                                                  const float* __restrict__ bias,
                                                  float* __restrict__ partM,
                                                  float* __restrict__ partS) {
  int lane = threadIdx.x & 63, w = threadIdx.x >> 6;
  int q = lane >> 4, c = lane & 15;
  int cb = blockIdx.x;
  int row0 = blockIdx.y * 64, n0 = cb * 64;
  const unsigned short* Arow = A + (size_t)(row0 + w * 16 + c) * D;
  f32x4 acc[4] = {{0.f,0.f,0.f,0.f},{0.f,0.f,0.f,0.f},{0.f,0.f,0.f,0.f},{0.f,0.f,0.f,0.f}};
#pragma unroll
  for (int kk = 0; kk < D; kk += 32) {
    bf16x8 a = *(const bf16x8*)(Arow + kk + q * 8);
#pragma unroll
    for (int t = 0; t < 4; t++) {
      bf16x8 bb = *(const bf16x8*)(Wt + (size_t)(n0 + t * 16 + c) * D + kk + q * 8);
      acc[t] = __builtin_amdgcn_mfma_f32_16x16x32_bf16(a, bb, acc[t], 0, 0, 0);
    }
  }
  float bv[4]; int vc[4];
#pragma unroll
  for (int t = 0; t < 4; t++) {
    vc[t] = n0 + t * 16 + c;
    bv[t] = (vc[t] < V) ? bias[vc[t]] : 0.f;
  }
#pragma unroll
  for (int r = 0; r < 4; r++) {
    float x[4]; float m = NEG_INF;
#pragma unroll
    for (int t = 0; t < 4; t++) {
      x[t] = (vc[t] < V) ? (acc[t][r] + bv[t]) : NEG_INF;
      m = fmaxf(m, x[t]);
    }
#pragma unroll
    for (int o = 1; o < 16; o <<= 1) m = fmaxf(m, __shfl_xor(m, o));
    float s = 0.f;
#pragma unroll
    for (int t = 0; t < 4; t++) s += __expf(x[t] - m);
#pragma unroll
    for (int o = 1; o < 16; o <<= 1) s += __shfl_xor(s, o);
    if (c == 0) {
      int row = row0 + w * 16 + q * 4 + r;
      partM[(size_t)cb * ROWS + row] = m;
      partS[(size_t)cb * ROWS + row] = s;
    }
  }
}

// ---- combine 79 partials -> lse[row] ----
__global__ __launch_bounds__(256) void k_lse(const float* __restrict__ pM,
                                             const float* __restrict__ pS,
                                             float* __restrict__ lse) {
  int row = blockIdx.x * 256 + threadIdx.x;
  float m = pM[row], s = pS[row];
  for (int cb = 1; cb < NCB; cb++) {
    float M2 = pM[(size_t)cb * ROWS + row], S2 = pS[(size_t)cb * ROWS + row];
    float mn = fmaxf(m, M2);
    s = s * __expf(m - mn) + S2 * __expf(M2 - mn);
    m = mn;
  }
  lse[row] = m + __logf(s);
}

// ---- gathered logits at extended labels: glog[b,t,s] = <hs,W[:,ext]> + b[ext] - lse ----
// grid (13 s-tiles, 50 t-tiles, 16 b), 64 thr (1 wave) per 16x16 tile
__global__ __launch_bounds__(64) void k_gather(const unsigned short* __restrict__ A,
                                               const unsigned short* __restrict__ Wt,
                                               const float* __restrict__ bias,
                                               const int* __restrict__ labels,
                                               const float* __restrict__ lse,
                                               float* __restrict__ glog) {
  int lane = threadIdx.x, q = lane >> 4, c = lane & 15;
  int b = blockIdx.z, t0 = blockIdx.y * 16, s0 = blockIdx.x * 16;
  int s = s0 + c;
  int ev = (s < S && (s & 1)) ? labels[b * L + (s >> 1)] : 0;
  const unsigned short* Brow = Wt + (size_t)ev * D;
  const unsigned short* Arow = A + (size_t)(b * T + t0 + c) * D;
  f32x4 acc = {0.f, 0.f, 0.f, 0.f};
#pragma unroll
  for (int kk = 0; kk < D; kk += 32) {
    bf16x8 a = *(const bf16x8*)(Arow + kk + q * 8);
    bf16x8 bb = *(const bf16x8*)(Brow + kk + q * 8);
    acc = __builtin_amdgcn_mfma_f32_16x16x32_bf16(a, bb, acc, 0, 0, 0);
  }
  float bs = bias[ev];
#pragma unroll
  for (int r = 0; r < 4; r++) {
    int row = b * T + t0 + q * 4 + r;
    glog[(size_t)row * SP + s0 + c] = acc[r] + bs - lse[row];
  }
}

// ---- CTC forward DP, one block per utterance ----
__global__ __launch_bounds__(256) void k_dp(const float* __restrict__ glog,
                                            const int* __restrict__ labels,
                                            const int* __restrict__ hlens,
                                            const int* __restrict__ llens,
                                            float* __restrict__ tot) {
  int b = blockIdx.x, tid = threadIdx.x;
  __shared__ float buf[2][S];
  __shared__ int ext[S];
  __shared__ unsigned char sk[S];
  if (tid < S) ext[tid] = (tid & 1) ? labels[b * L + (tid >> 1)] : 0;
  __syncthreads();
  if (tid < S) {
    sk[tid] = (tid >= 2) && (ext[tid] != 0) && (ext[tid] != ext[tid - 2]);
    buf[0][tid] = (tid < 2) ? glog[(size_t)(b * T) * SP + tid] : NEG_INF;
  }
  int hl = hlens[b];
  __syncthreads();
  int p = 0;
  float gnext = (tid < S && hl > 1) ? glog[(size_t)(b * T + 1) * SP + tid] : 0.f;
  for (int t = 1; t < hl; t++) {
    float g = gnext;
    if (t + 1 < hl && tid < S) gnext = glog[(size_t)(b * T + t + 1) * SP + tid];
    if (tid < S) {
      float v0 = buf[p][tid];
      float v1 = (tid >= 1) ? buf[p][tid - 1] : NEG_INF;
      float v2 = (tid >= 2 && sk[tid]) ? buf[p][tid - 2] : NEG_INF;
      float m = fmaxf(v0, fmaxf(v1, v2));
      float ssum = __expf(v0 - m) + __expf(v1 - m) + __expf(v2 - m);
      buf[p ^ 1][tid] = m + __logf(ssum) + g;
    }
    __syncthreads();
    p ^= 1;
  }
  if (tid == 0) {
    int ll = llens[b];
    float aL = buf[p][2 * ll], aP = buf[p][2 * ll - 1];
    float m = fmaxf(aL, aP);
    tot[b] = m + __logf(__expf(aL - m) + __expf(aP - m));
  }
}

// ---- mean of -tot -> out[0] ----
__global__ void k_final(const float* __restrict__ tot, float* __restrict__ out) {
  int lane = threadIdx.x;
  float v = (lane < Bb) ? tot[lane] : 0.f;
#pragma unroll
  for (int o = 1; o < 16; o <<= 1) v += __shfl_xor(v, o);
  if (lane == 0) out[0] = -v / (float)Bb;
}

extern "C" void kernel_launch(void* const* d_in, const int* in_sizes, int n_in,
                              void* d_out, int out_size, void* d_ws, size_t ws_size,
                              hipStream_t stream) {
  const float* hs    = (const float*)d_in[0];
  const float* W     = (const float*)d_in[1];
  const float* bias  = (const float*)d_in[2];
  const int* hlens   = (const int*)d_in[3];
  const int* labels  = (const int*)d_in[4];
  const int* llens   = (const int*)d_in[5];
  float* out = (float*)d_out;

  char* ws = (char*)d_ws;
  // workspace layout (bytes), all 256-aligned; total 37,075,008
  unsigned short* A    = (unsigned short*)(ws);              // 12800*512*2  = 13,107,200
  unsigned short* Wt   = (unsigned short*)(ws + 13107200);   // 5056*512*2   =  5,177,344
  float*          partM= (float*)(ws + 18284544);            // 79*12800*4   =  4,044,800
  float*          partS= (float*)(ws + 22329344);            // 79*12800*4   =  4,044,800
  float*          lse  = (float*)(ws + 26374144);            // 12800*4      =     51,200
  float*          glog = (float*)(ws + 26425344);            // 12800*208*4  = 10,649,600
  float*          tot  = (float*)(ws + 37074944);            // 16*4

  k_conv_hs<<<ROWS * D / 1024, 256, 0, stream>>>(hs, A);
  k_transW<<<dim3(NCB, D / 64), 256, 0, stream>>>(W, Wt);
  k_gemm_lse<<<dim3(NCB, NRB), 256, 0, stream>>>(A, Wt, bias, partM, partS);
  k_lse<<<ROWS / 256, 256, 0, stream>>>(partM, partS, lse);
  k_gather<<<dim3(SP / 16, T / 16, Bb), 64, 0, stream>>>(A, Wt, bias, labels, lse, glog);
  k_dp<<<Bb, 256, 0, stream>>>(glog, labels, hlens, llens, tot);
  k_final<<<1, 64, 0, stream>>>(tot, out);

  (void)in_sizes; (void)n_in; (void)out_size; (void)ws_size;
}

// Round 2
// 491.171 us; speedup vs baseline: 1.8256x; 1.8256x over previous
//
#include <hip/hip_runtime.h>

#define NEG_INF -1e30f

typedef __attribute__((ext_vector_type(8))) __bf16 bf16x8;
typedef __attribute__((ext_vector_type(4))) float f32x4;

constexpr int Bb = 16, T = 800, D = 512, V = 5000, L = 100;
constexpr int ROWS = Bb * T;        // 12800
constexpr int S = 2 * L + 1;        // 201
constexpr int SP = 208;             // padded S (13*16)
constexpr int VP = 5120;            // V padded to 128
constexpr int NCB = VP / 128;       // 40 col-blocks (GEMM)
constexpr int NRB = ROWS / 128;     // 100 row-blocks

// float -> bf16 bits, round-to-nearest-even
static __device__ __forceinline__ unsigned short f2bf(float x) {
  union { float f; unsigned u; } v; v.f = x;
  unsigned r = (v.u + 0x7FFFu + ((v.u >> 16) & 1u)) >> 16;
  return (unsigned short)r;
}

// ---- hs fp32 -> bf16 (row-major [12800][512]) ----
__global__ __launch_bounds__(256) void k_conv_hs(const float* __restrict__ hs,
                                                 unsigned short* __restrict__ A) {
  int i = blockIdx.x * 256 + threadIdx.x;
  float4 f = ((const float4*)hs)[i];
  ushort4 o;
  o.x = f2bf(f.x); o.y = f2bf(f.y); o.z = f2bf(f.z); o.w = f2bf(f.w);
  ((ushort4*)A)[i] = o;
}

// ---- W [512][5000] fp32 -> Wt [5120][512] bf16 (transposed, pad rows zero) ----
__global__ __launch_bounds__(256) void k_transW(const float* __restrict__ W,
                                                unsigned short* __restrict__ Wt) {
  __shared__ float tile[64][65];
  int v0 = blockIdx.x * 64, k0 = blockIdx.y * 64;
  int tl = threadIdx.x & 63, th = threadIdx.x >> 6;
#pragma unroll
  for (int i = 0; i < 16; i++) {
    int k = k0 + th + i * 4;
    int v = v0 + tl;
    tile[th + i * 4][tl] = (v < V) ? W[(size_t)k * V + v] : 0.f;
  }
  __syncthreads();
#pragma unroll
  for (int i = 0; i < 16; i++) {
    int v = v0 + th + i * 4;
    int k = k0 + tl;
    Wt[(size_t)v * D + k] = f2bf(tile[tl][th + i * 4]);
  }
}

// ---- fused 128x128 GEMM + per-row online softmax partials (m97 structure) ----
// grid (40 colblocks, 100 rowblocks), 256 thr = 2x2 waves of 64x64.
__global__ __launch_bounds__(256) void k_gemm_lse(const unsigned short* __restrict__ A,
                                                  const unsigned short* __restrict__ Wt,
                                                  const float* __restrict__ bias,
                                                  float* __restrict__ partM,
                                                  float* __restrict__ partS) {
  __shared__ unsigned short As[128 * 64];   // [row][k] 128x64
  __shared__ unsigned short Bs[128 * 64];   // [col][k] 128x64
  __shared__ float redM[2][128];
  __shared__ float redS[2][128];

  int tid = threadIdx.x;
  int lane = tid & 63, w = tid >> 6;
  int q = lane >> 4, c = lane & 15;
  int mh = w & 1, nh = w >> 1;          // wave's 64x64 quadrant
  int cb = blockIdx.x;
  int row0 = blockIdx.y * 128, n0 = cb * 128;
  int lr = lane >> 3, lc = lane & 7;    // staging: 8 rows x 8 k-octets per instr

  f32x4 acc[4][4];
#pragma unroll
  for (int mt = 0; mt < 4; mt++)
#pragma unroll
    for (int nt = 0; nt < 4; nt++) acc[mt][nt] = (f32x4){0.f, 0.f, 0.f, 0.f};

  for (int kk = 0; kk < D; kk += 64) {
#pragma unroll
    for (int j = 0; j < 4; j++) {
      int i = w * 4 + j;                 // instr covers tile rows i*8..i*8+7
      const unsigned short* ga = A + (size_t)(row0 + i * 8 + lr) * D + kk + lc * 8;
      __builtin_amdgcn_global_load_lds(
          (const __attribute__((address_space(1))) void*)ga,
          (__attribute__((address_space(3))) void*)(As + i * 512), 16, 0, 0);
      const unsigned short* gb = Wt + (size_t)(n0 + i * 8 + lr) * D + kk + lc * 8;
      __builtin_amdgcn_global_load_lds(
          (const __attribute__((address_space(1))) void*)gb,
          (__attribute__((address_space(3))) void*)(Bs + i * 512), 16, 0, 0);
    }
    __syncthreads();
#pragma unroll
    for (int kq = 0; kq < 2; kq++) {
      bf16x8 af[4], bfr[4];
#pragma unroll
      for (int mt = 0; mt < 4; mt++)
        af[mt] = *(const bf16x8*)(As + (mh * 64 + mt * 16 + c) * 64 + kq * 32 + q * 8);
#pragma unroll
      for (int nt = 0; nt < 4; nt++)
        bfr[nt] = *(const bf16x8*)(Bs + (nh * 64 + nt * 16 + c) * 64 + kq * 32 + q * 8);
#pragma unroll
      for (int mt = 0; mt < 4; mt++)
#pragma unroll
        for (int nt = 0; nt < 4; nt++)
          acc[mt][nt] = __builtin_amdgcn_mfma_f32_16x16x32_bf16(af[mt], bfr[nt], acc[mt][nt], 0, 0, 0);
    }
    __syncthreads();
  }

  // epilogue: per-row max / sum-exp over this wave's 64 cols
  int vcb[4]; float bv[4];
#pragma unroll
  for (int nt = 0; nt < 4; nt++) {
    vcb[nt] = n0 + nh * 64 + nt * 16 + c;
    bv[nt] = (vcb[nt] < V) ? bias[vcb[nt]] : 0.f;
  }
#pragma unroll
  for (int mt = 0; mt < 4; mt++) {
#pragma unroll
    for (int r = 0; r < 4; r++) {
      float x[4]; float m = NEG_INF;
#pragma unroll
      for (int nt = 0; nt < 4; nt++) {
        x[nt] = (vcb[nt] < V) ? (acc[mt][nt][r] + bv[nt]) : NEG_INF;
        m = fmaxf(m, x[nt]);
      }
#pragma unroll
      for (int o = 1; o < 16; o <<= 1) m = fmaxf(m, __shfl_xor(m, o));
      float s = 0.f;
#pragma unroll
      for (int nt = 0; nt < 4; nt++) s += __expf(x[nt] - m);
#pragma unroll
      for (int o = 1; o < 16; o <<= 1) s += __shfl_xor(s, o);
      if (c == 0) {
        int rloc = mh * 64 + mt * 16 + q * 4 + r;
        redM[nh][rloc] = m;
        redS[nh][rloc] = s;
      }
    }
  }
  __syncthreads();
  if (tid < 128) {
    float m0 = redM[0][tid], m1 = redM[1][tid];
    float mm = fmaxf(m0, m1);
    float ss = redS[0][tid] * __expf(m0 - mm) + redS[1][tid] * __expf(m1 - mm);
    partM[(size_t)cb * ROWS + row0 + tid] = mm;
    partS[(size_t)cb * ROWS + row0 + tid] = ss;
  }
}

// ---- combine 40 partials -> lse[row] ----
__global__ __launch_bounds__(256) void k_lse(const float* __restrict__ pM,
                                             const float* __restrict__ pS,
                                             float* __restrict__ lse) {
  int row = blockIdx.x * 256 + threadIdx.x;
  float m = pM[row], s = pS[row];
  for (int cb = 1; cb < NCB; cb++) {
    float M2 = pM[(size_t)cb * ROWS + row], S2 = pS[(size_t)cb * ROWS + row];
    float mn = fmaxf(m, M2);
    s = s * __expf(m - mn) + S2 * __expf(M2 - mn);
    m = mn;
  }
  lse[row] = m + __logf(s);
}

// ---- gathered logits at extended labels: glog[b,t,s] = <hs,W[:,ext]> + b[ext] - lse ----
__global__ __launch_bounds__(64) void k_gather(const unsigned short* __restrict__ A,
                                               const unsigned short* __restrict__ Wt,
                                               const float* __restrict__ bias,
                                               const int* __restrict__ labels,
                                               const float* __restrict__ lse,
                                               float* __restrict__ glog) {
  int lane = threadIdx.x, q = lane >> 4, c = lane & 15;
  int b = blockIdx.z, t0 = blockIdx.y * 16, s0 = blockIdx.x * 16;
  int s = s0 + c;
  int ev = (s < S && (s & 1)) ? labels[b * L + (s >> 1)] : 0;
  const unsigned short* Brow = Wt + (size_t)ev * D;
  const unsigned short* Arow = A + (size_t)(b * T + t0 + c) * D;
  f32x4 acc = {0.f, 0.f, 0.f, 0.f};
#pragma unroll
  for (int kk = 0; kk < D; kk += 32) {
    bf16x8 a = *(const bf16x8*)(Arow + kk + q * 8);
    bf16x8 bb = *(const bf16x8*)(Brow + kk + q * 8);
    acc = __builtin_amdgcn_mfma_f32_16x16x32_bf16(a, bb, acc, 0, 0, 0);
  }
  float bs = bias[ev];
#pragma unroll
  for (int r = 0; r < 4; r++) {
    int row = b * T + t0 + q * 4 + r;
    glog[(size_t)row * SP + s0 + c] = acc[r] + bs - lse[row];
  }
}

// ---- CTC forward DP, one block per utterance ----
__global__ __launch_bounds__(256) void k_dp(const float* __restrict__ glog,
                                            const int* __restrict__ labels,
                                            const int* __restrict__ hlens,
                                            const int* __restrict__ llens,
                                            float* __restrict__ tot) {
  int b = blockIdx.x, tid = threadIdx.x;
  __shared__ float buf[2][S];
  __shared__ int ext[S];
  __shared__ unsigned char sk[S];
  if (tid < S) ext[tid] = (tid & 1) ? labels[b * L + (tid >> 1)] : 0;
  __syncthreads();
  if (tid < S) {
    sk[tid] = (tid >= 2) && (ext[tid] != 0) && (ext[tid] != ext[tid - 2]);
    buf[0][tid] = (tid < 2) ? glog[(size_t)(b * T) * SP + tid] : NEG_INF;
  }
  int hl = hlens[b];
  __syncthreads();
  int p = 0;
  float gnext = (tid < S && hl > 1) ? glog[(size_t)(b * T + 1) * SP + tid] : 0.f;
  for (int t = 1; t < hl; t++) {
    float g = gnext;
    if (t + 1 < hl && tid < S) gnext = glog[(size_t)(b * T + t + 1) * SP + tid];
    if (tid < S) {
      float v0 = buf[p][tid];
      float v1 = (tid >= 1) ? buf[p][tid - 1] : NEG_INF;
      float v2 = (tid >= 2 && sk[tid]) ? buf[p][tid - 2] : NEG_INF;
      float m = fmaxf(v0, fmaxf(v1, v2));
      float ssum = __expf(v0 - m) + __expf(v1 - m) + __expf(v2 - m);
      buf[p ^ 1][tid] = m + __logf(ssum) + g;
    }
    __syncthreads();
    p ^= 1;
  }
  if (tid == 0) {
    int ll = llens[b];
    float aL = buf[p][2 * ll], aP = buf[p][2 * ll - 1];
    float m = fmaxf(aL, aP);
    tot[b] = m + __logf(__expf(aL - m) + __expf(aP - m));
  }
}

// ---- mean of -tot -> out[0] ----
__global__ void k_final(const float* __restrict__ tot, float* __restrict__ out) {
  int lane = threadIdx.x;
  float v = (lane < Bb) ? tot[lane] : 0.f;
#pragma unroll
  for (int o = 1; o < 16; o <<= 1) v += __shfl_xor(v, o);
  if (lane == 0) out[0] = -v / (float)Bb;
}

extern "C" void kernel_launch(void* const* d_in, const int* in_sizes, int n_in,
                              void* d_out, int out_size, void* d_ws, size_t ws_size,
                              hipStream_t stream) {
  const float* hs    = (const float*)d_in[0];
  const float* W     = (const float*)d_in[1];
  const float* bias  = (const float*)d_in[2];
  const int* hlens   = (const int*)d_in[3];
  const int* labels  = (const int*)d_in[4];
  const int* llens   = (const int*)d_in[5];
  float* out = (float*)d_out;

  char* ws = (char*)d_ws;
  // workspace layout (bytes); total 33,146,944
  unsigned short* A    = (unsigned short*)(ws);              // 12800*512*2 = 13,107,200
  unsigned short* Wt   = (unsigned short*)(ws + 13107200);   // 5120*512*2  =  5,242,880
  float*          partM= (float*)(ws + 18350080);            // 40*12800*4  =  2,048,000
  float*          partS= (float*)(ws + 20398080);            // 40*12800*4  =  2,048,000
  float*          lse  = (float*)(ws + 22446080);            // 12800*4     =     51,200
  float*          glog = (float*)(ws + 22497280);            // 12800*208*4 = 10,649,600
  float*          tot  = (float*)(ws + 33146880);            // 16*4

  k_conv_hs<<<ROWS * D / 1024, 256, 0, stream>>>(hs, A);
  k_transW<<<dim3(VP / 64, D / 64), 256, 0, stream>>>(W, Wt);
  k_gemm_lse<<<dim3(NCB, NRB), 256, 0, stream>>>(A, Wt, bias, partM, partS);
  k_lse<<<ROWS / 256, 256, 0, stream>>>(partM, partS, lse);
  k_gather<<<dim3(SP / 16, T / 16, Bb), 64, 0, stream>>>(A, Wt, bias, labels, lse, glog);
  k_dp<<<Bb, 256, 0, stream>>>(glog, labels, hlens, llens, tot);
  k_final<<<1, 64, 0, stream>>>(tot, out);

  (void)in_sizes; (void)n_in; (void)out_size; (void)ws_size;
}

// Round 3
// 484.191 us; speedup vs baseline: 1.8519x; 1.0144x over previous
//
#include <hip/hip_runtime.h>

#define NEG_INF -1e30f

typedef __attribute__((ext_vector_type(8))) __bf16 bf16x8;
typedef __attribute__((ext_vector_type(4))) float f32x4;

constexpr int Bb = 16, T = 800, D = 512, V = 5000, L = 100;
constexpr int ROWS = Bb * T;        // 12800
constexpr int S = 2 * L + 1;        // 201
constexpr int SP = 208;             // padded S (13*16)
constexpr int VP = 5120;            // V padded to 128
constexpr int NCB = VP / 128;       // 40 col-blocks (GEMM)
constexpr int NRB = ROWS / 128;     // 100 row-blocks

// float -> bf16 bits, round-to-nearest-even
static __device__ __forceinline__ unsigned short f2bf(float x) {
  union { float f; unsigned u; } v; v.f = x;
  unsigned r = (v.u + 0x7FFFu + ((v.u >> 16) & 1u)) >> 16;
  return (unsigned short)r;
}

// ---- hs fp32 -> bf16 (row-major [12800][512]) ----
__global__ __launch_bounds__(256) void k_conv_hs(const float* __restrict__ hs,
                                                 unsigned short* __restrict__ A) {
  int i = blockIdx.x * 256 + threadIdx.x;
  float4 f = ((const float4*)hs)[i];
  ushort4 o;
  o.x = f2bf(f.x); o.y = f2bf(f.y); o.z = f2bf(f.z); o.w = f2bf(f.w);
  ((ushort4*)A)[i] = o;
}

// ---- W [512][5000] fp32 -> Wt [5120][512] bf16 (transposed, pad rows zero) ----
__global__ __launch_bounds__(256) void k_transW(const float* __restrict__ W,
                                                unsigned short* __restrict__ Wt) {
  __shared__ float tile[64][65];
  int v0 = blockIdx.x * 64, k0 = blockIdx.y * 64;
  int tl = threadIdx.x & 63, th = threadIdx.x >> 6;
#pragma unroll
  for (int i = 0; i < 16; i++) {
    int k = k0 + th + i * 4;
    int v = v0 + tl;
    tile[th + i * 4][tl] = (v < V) ? W[(size_t)k * V + v] : 0.f;
  }
  __syncthreads();
#pragma unroll
  for (int i = 0; i < 16; i++) {
    int v = v0 + th + i * 4;
    int k = k0 + tl;
    Wt[(size_t)v * D + k] = f2bf(tile[tl][th + i * 4]);
  }
}

// ---- fused 128x128 GEMM + per-row online softmax partials (m97 structure) ----
__global__ __launch_bounds__(256) void k_gemm_lse(const unsigned short* __restrict__ A,
                                                  const unsigned short* __restrict__ Wt,
                                                  const float* __restrict__ bias,
                                                  float* __restrict__ partM,
                                                  float* __restrict__ partS) {
  __shared__ unsigned short As[128 * 64];   // [row][k] 128x64
  __shared__ unsigned short Bs[128 * 64];   // [col][k] 128x64
  __shared__ float redM[2][128];
  __shared__ float redS[2][128];

  int tid = threadIdx.x;
  int lane = tid & 63, w = tid >> 6;
  int q = lane >> 4, c = lane & 15;
  int mh = w & 1, nh = w >> 1;          // wave's 64x64 quadrant
  int cb = blockIdx.x;
  int row0 = blockIdx.y * 128, n0 = cb * 128;
  int lr = lane >> 3, lc = lane & 7;    // staging: 8 rows x 8 k-octets per instr

  f32x4 acc[4][4];
#pragma unroll
  for (int mt = 0; mt < 4; mt++)
#pragma unroll
    for (int nt = 0; nt < 4; nt++) acc[mt][nt] = (f32x4){0.f, 0.f, 0.f, 0.f};

  for (int kk = 0; kk < D; kk += 64) {
#pragma unroll
    for (int j = 0; j < 4; j++) {
      int i = w * 4 + j;
      const unsigned short* ga = A + (size_t)(row0 + i * 8 + lr) * D + kk + lc * 8;
      __builtin_amdgcn_global_load_lds(
          (const __attribute__((address_space(1))) void*)ga,
          (__attribute__((address_space(3))) void*)(As + i * 512), 16, 0, 0);
      const unsigned short* gb = Wt + (size_t)(n0 + i * 8 + lr) * D + kk + lc * 8;
      __builtin_amdgcn_global_load_lds(
          (const __attribute__((address_space(1))) void*)gb,
          (__attribute__((address_space(3))) void*)(Bs + i * 512), 16, 0, 0);
    }
    __syncthreads();
#pragma unroll
    for (int kq = 0; kq < 2; kq++) {
      bf16x8 af[4], bfr[4];
#pragma unroll
      for (int mt = 0; mt < 4; mt++)
        af[mt] = *(const bf16x8*)(As + (mh * 64 + mt * 16 + c) * 64 + kq * 32 + q * 8);
#pragma unroll
      for (int nt = 0; nt < 4; nt++)
        bfr[nt] = *(const bf16x8*)(Bs + (nh * 64 + nt * 16 + c) * 64 + kq * 32 + q * 8);
#pragma unroll
      for (int mt = 0; mt < 4; mt++)
#pragma unroll
        for (int nt = 0; nt < 4; nt++)
          acc[mt][nt] = __builtin_amdgcn_mfma_f32_16x16x32_bf16(af[mt], bfr[nt], acc[mt][nt], 0, 0, 0);
    }
    __syncthreads();
  }

  int vcb[4]; float bv[4];
#pragma unroll
  for (int nt = 0; nt < 4; nt++) {
    vcb[nt] = n0 + nh * 64 + nt * 16 + c;
    bv[nt] = (vcb[nt] < V) ? bias[vcb[nt]] : 0.f;
  }
#pragma unroll
  for (int mt = 0; mt < 4; mt++) {
#pragma unroll
    for (int r = 0; r < 4; r++) {
      float x[4]; float m = NEG_INF;
#pragma unroll
      for (int nt = 0; nt < 4; nt++) {
        x[nt] = (vcb[nt] < V) ? (acc[mt][nt][r] + bv[nt]) : NEG_INF;
        m = fmaxf(m, x[nt]);
      }
#pragma unroll
      for (int o = 1; o < 16; o <<= 1) m = fmaxf(m, __shfl_xor(m, o));
      float s = 0.f;
#pragma unroll
      for (int nt = 0; nt < 4; nt++) s += __expf(x[nt] - m);
#pragma unroll
      for (int o = 1; o < 16; o <<= 1) s += __shfl_xor(s, o);
      if (c == 0) {
        int rloc = mh * 64 + mt * 16 + q * 4 + r;
        redM[nh][rloc] = m;
        redS[nh][rloc] = s;
      }
    }
  }
  __syncthreads();
  if (tid < 128) {
    float m0 = redM[0][tid], m1 = redM[1][tid];
    float mm = fmaxf(m0, m1);
    float ss = redS[0][tid] * __expf(m0 - mm) + redS[1][tid] * __expf(m1 - mm);
    partM[(size_t)cb * ROWS + row0 + tid] = mm;
    partS[(size_t)cb * ROWS + row0 + tid] = ss;
  }
}

// ---- combine 40 partials -> lse[row] ----
__global__ __launch_bounds__(256) void k_lse(const float* __restrict__ pM,
                                             const float* __restrict__ pS,
                                             float* __restrict__ lse) {
  int row = blockIdx.x * 256 + threadIdx.x;
  float m = pM[row], s = pS[row];
  for (int cb = 1; cb < NCB; cb++) {
    float M2 = pM[(size_t)cb * ROWS + row], S2 = pS[(size_t)cb * ROWS + row];
    float mn = fmaxf(m, M2);
    s = s * __expf(m - mn) + S2 * __expf(M2 - mn);
    m = mn;
  }
  lse[row] = m + __logf(s);
}

// ---- gathered logits at extended labels ----
__global__ __launch_bounds__(64) void k_gather(const unsigned short* __restrict__ A,
                                               const unsigned short* __restrict__ Wt,
                                               const float* __restrict__ bias,
                                               const int* __restrict__ labels,
                                               const float* __restrict__ lse,
                                               float* __restrict__ glog) {
  int lane = threadIdx.x, q = lane >> 4, c = lane & 15;
  int b = blockIdx.z, t0 = blockIdx.y * 16, s0 = blockIdx.x * 16;
  int s = s0 + c;
  int ev = (s < S && (s & 1)) ? labels[b * L + (s >> 1)] : 0;
  const unsigned short* Brow = Wt + (size_t)ev * D;
  const unsigned short* Arow = A + (size_t)(b * T + t0 + c) * D;
  f32x4 acc = {0.f, 0.f, 0.f, 0.f};
#pragma unroll
  for (int kk = 0; kk < D; kk += 32) {
    bf16x8 a = *(const bf16x8*)(Arow + kk + q * 8);
    bf16x8 bb = *(const bf16x8*)(Brow + kk + q * 8);
    acc = __builtin_amdgcn_mfma_f32_16x16x32_bf16(a, bb, acc, 0, 0, 0);
  }
  float bs = bias[ev];
#pragma unroll
  for (int r = 0; r < 4; r++) {
    int row = b * T + t0 + q * 4 + r;
    glog[(size_t)row * SP + s0 + c] = acc[r] + bs - lse[row];
  }
}

// ---- CTC forward DP: one WAVE per utterance, 4 states/lane, no barriers ----
__global__ __launch_bounds__(64) void k_dp(const float* __restrict__ glog,
                                           const int* __restrict__ labels,
                                           const int* __restrict__ hlens,
                                           const int* __restrict__ llens,
                                           float* __restrict__ tot) {
  int b = blockIdx.x, l = threadIdx.x;
  const float* gbase = glog + (size_t)(b * T) * SP;
  bool ld = (4 * l < SP);  // lanes 0..51 hold live states

  // skip masks for this lane's odd states s=4l+1, s=4l+3
  int lab0 = (2 * l < L) ? labels[b * L + 2 * l] : 0;          // ext[4l+1]
  int lab1 = (2 * l + 1 < L) ? labels[b * L + 2 * l + 1] : 0;  // ext[4l+3]
  int labm = (l >= 1 && 2 * l - 1 < L) ? labels[b * L + 2 * l - 1] : 0;  // ext[4l-1]
  bool sk1 = (4 * l + 1 >= 2) && (lab0 != 0) && (lab0 != labm);
  bool sk3 = (lab1 != 0) && (lab1 != lab0);
  int hl = hlens[b];

  // init at t=0: alpha[0], alpha[1] from row 0, rest NEG_INF
  float4 g0 = ld ? *(const float4*)(gbase + 4 * l) : make_float4(0.f, 0.f, 0.f, 0.f);
  float a0 = (l == 0) ? g0.x : NEG_INF;
  float a1 = (l == 0) ? g0.y : NEG_INF;
  float a2 = NEG_INF, a3 = NEG_INF;

  constexpr int CH = 8;
  float4 cur[CH], nxt[CH];
  int nsteps = hl - 1;  // steps t=1..hl-1
#pragma unroll
  for (int j = 0; j < CH; j++) {
    int t = 1 + j; t = t < hl ? t : hl - 1;
    cur[j] = ld ? *(const float4*)(gbase + (size_t)t * SP + 4 * l) : make_float4(0.f,0.f,0.f,0.f);
  }
  for (int u0 = 0; u0 < nsteps; u0 += CH) {
#pragma unroll
    for (int j = 0; j < CH; j++) {
      int t = u0 + CH + 1 + j; t = t < hl ? t : hl - 1;
      nxt[j] = ld ? *(const float4*)(gbase + (size_t)t * SP + 4 * l) : make_float4(0.f,0.f,0.f,0.f);
    }
#pragma unroll
    for (int j = 0; j < CH; j++) {
      if (u0 + j >= nsteps) break;
      float4 g = cur[j];
      float p3 = __shfl_up(a3, 1);
      float p2 = __shfl_up(a2, 1);
      if (l == 0) { p3 = NEG_INF; p2 = NEG_INF; }
      // even states (never skip): 2-way logaddexp; odd states: 3-way gated
      float m0 = fmaxf(a0, p3);
      float n0 = m0 + __logf(__expf(a0 - m0) + __expf(p3 - m0)) + g.x;
      float v21 = sk1 ? p2 : NEG_INF;
      float m1 = fmaxf(fmaxf(a1, a0), v21);
      float n1 = m1 + __logf(__expf(a1 - m1) + __expf(a0 - m1) + __expf(v21 - m1)) + g.y;
      float m2 = fmaxf(a2, a1);
      float n2 = m2 + __logf(__expf(a2 - m2) + __expf(a1 - m2)) + g.z;
      float v23 = sk3 ? a1 : NEG_INF;
      float m3 = fmaxf(fmaxf(a3, a2), v23);
      float n3 = m3 + __logf(__expf(a3 - m3) + __expf(a2 - m3) + __expf(v23 - m3)) + g.w;
      a0 = n0; a1 = n1; a2 = n2; a3 = n3;
    }
#pragma unroll
    for (int j = 0; j < CH; j++) cur[j] = nxt[j];
  }

  __shared__ float fin[256];
  fin[4 * l] = a0; fin[4 * l + 1] = a1; fin[4 * l + 2] = a2; fin[4 * l + 3] = a3;
  __syncthreads();
  if (l == 0) {
    int ll = llens[b];
    float aL = fin[2 * ll], aP = fin[2 * ll - 1];
    float m = fmaxf(aL, aP);
    tot[b] = m + __logf(__expf(aL - m) + __expf(aP - m));
  }
}

// ---- mean of -tot -> out[0] ----
__global__ void k_final(const float* __restrict__ tot, float* __restrict__ out) {
  int lane = threadIdx.x;
  float v = (lane < Bb) ? tot[lane] : 0.f;
#pragma unroll
  for (int o = 1; o < 16; o <<= 1) v += __shfl_xor(v, o);
  if (lane == 0) out[0] = -v / (float)Bb;
}

extern "C" void kernel_launch(void* const* d_in, const int* in_sizes, int n_in,
                              void* d_out, int out_size, void* d_ws, size_t ws_size,
                              hipStream_t stream) {
  const float* hs    = (const float*)d_in[0];
  const float* W     = (const float*)d_in[1];
  const float* bias  = (const float*)d_in[2];
  const int* hlens   = (const int*)d_in[3];
  const int* labels  = (const int*)d_in[4];
  const int* llens   = (const int*)d_in[5];
  float* out = (float*)d_out;

  char* ws = (char*)d_ws;
  unsigned short* A    = (unsigned short*)(ws);              // 12800*512*2 = 13,107,200
  unsigned short* Wt   = (unsigned short*)(ws + 13107200);   // 5120*512*2  =  5,242,880
  float*          partM= (float*)(ws + 18350080);            // 40*12800*4  =  2,048,000
  float*          partS= (float*)(ws + 20398080);            // 40*12800*4  =  2,048,000
  float*          lse  = (float*)(ws + 22446080);            // 12800*4     =     51,200
  float*          glog = (float*)(ws + 22497280);            // 12800*208*4 = 10,649,600
  float*          tot  = (float*)(ws + 33146880);            // 16*4

  k_conv_hs<<<ROWS * D / 1024, 256, 0, stream>>>(hs, A);
  k_transW<<<dim3(VP / 64, D / 64), 256, 0, stream>>>(W, Wt);
  k_gemm_lse<<<dim3(NCB, NRB), 256, 0, stream>>>(A, Wt, bias, partM, partS);
  k_lse<<<ROWS / 256, 256, 0, stream>>>(partM, partS, lse);
  k_gather<<<dim3(SP / 16, T / 16, Bb), 64, 0, stream>>>(A, Wt, bias, labels, lse, glog);
  k_dp<<<Bb, 64, 0, stream>>>(glog, labels, hlens, llens, tot);
  k_final<<<1, 64, 0, stream>>>(tot, out);

  (void)in_sizes; (void)n_in; (void)out_size; (void)ws_size;
}

// Round 5
// 446.836 us; speedup vs baseline: 2.0067x; 1.0836x over previous
//
#include <hip/hip_runtime.h>

#define NEG_INF -1e30f

typedef __attribute__((ext_vector_type(8))) __bf16 bf16x8;
typedef __attribute__((ext_vector_type(4))) float f32x4;

constexpr int Bb = 16, T = 800, D = 512, V = 5000, L = 100;
constexpr int ROWS = Bb * T;        // 12800
constexpr int S = 2 * L + 1;        // 201
constexpr int SP = 208;             // padded S (13*16)
constexpr int VP = 5120;            // V padded to 128
constexpr int NCB = VP / 128;       // 40 col-blocks (GEMM)
constexpr int NRB = ROWS / 128;     // 100 row-blocks

// float -> bf16 bits, round-to-nearest-even
static __device__ __forceinline__ unsigned short f2bf(float x) {
  union { float f; unsigned u; } v; v.f = x;
  unsigned r = (v.u + 0x7FFFu + ((v.u >> 16) & 1u)) >> 16;
  return (unsigned short)r;
}

// wave_shr:1 (0x138): lane i gets lane i-1; lane 0 (no source, bound_ctrl=0)
// falls back to `old` = NEG_INF. Single VALU op on the DP chain.
static __device__ __forceinline__ float dpp_shr1_neginf(float x) {
  return __int_as_float(__builtin_amdgcn_update_dpp(
      __float_as_int(NEG_INF), __float_as_int(x), 0x138, 0xF, 0xF, false));
}

// ---- hs fp32 -> bf16 (row-major [12800][512]) ----
__global__ __launch_bounds__(256) void k_conv_hs(const float* __restrict__ hs,
                                                 unsigned short* __restrict__ A) {
  int i = blockIdx.x * 256 + threadIdx.x;
  float4 f = ((const float4*)hs)[i];
  ushort4 o;
  o.x = f2bf(f.x); o.y = f2bf(f.y); o.z = f2bf(f.z); o.w = f2bf(f.w);
  ((ushort4*)A)[i] = o;
}

// ---- W [512][5000] fp32 -> Wt [5120][512] bf16 (transposed, pad rows zero) ----
__global__ __launch_bounds__(256) void k_transW(const float* __restrict__ W,
                                                unsigned short* __restrict__ Wt) {
  __shared__ float tile[64][65];
  int v0 = blockIdx.x * 64, k0 = blockIdx.y * 64;
  int tl = threadIdx.x & 63, th = threadIdx.x >> 6;
#pragma unroll
  for (int i = 0; i < 16; i++) {
    int k = k0 + th + i * 4;
    int v = v0 + tl;
    tile[th + i * 4][tl] = (v < V) ? W[(size_t)k * V + v] : 0.f;
  }
  __syncthreads();
#pragma unroll
  for (int i = 0; i < 16; i++) {
    int v = v0 + th + i * 4;
    int k = k0 + tl;
    Wt[(size_t)v * D + k] = f2bf(tile[tl][th + i * 4]);
  }
}

// ---- fused 128x128 GEMM + per-row online softmax partials (m97 structure) ----
__global__ __launch_bounds__(256) void k_gemm_lse(const unsigned short* __restrict__ A,
                                                  const unsigned short* __restrict__ Wt,
                                                  const float* __restrict__ bias,
                                                  float* __restrict__ partM,
                                                  float* __restrict__ partS) {
  __shared__ unsigned short As[128 * 64];   // [row][k] 128x64
  __shared__ unsigned short Bs[128 * 64];   // [col][k] 128x64
  __shared__ float redM[2][128];
  __shared__ float redS[2][128];

  int tid = threadIdx.x;
  int lane = tid & 63, w = tid >> 6;
  int q = lane >> 4, c = lane & 15;
  int mh = w & 1, nh = w >> 1;          // wave's 64x64 quadrant
  int cb = blockIdx.x;
  int row0 = blockIdx.y * 128, n0 = cb * 128;
  int lr = lane >> 3, lc = lane & 7;    // staging: 8 rows x 8 k-octets per instr

  f32x4 acc[4][4];
#pragma unroll
  for (int mt = 0; mt < 4; mt++)
#pragma unroll
    for (int nt = 0; nt < 4; nt++) acc[mt][nt] = (f32x4){0.f, 0.f, 0.f, 0.f};

  for (int kk = 0; kk < D; kk += 64) {
#pragma unroll
    for (int j = 0; j < 4; j++) {
      int i = w * 4 + j;
      const unsigned short* ga = A + (size_t)(row0 + i * 8 + lr) * D + kk + lc * 8;
      __builtin_amdgcn_global_load_lds(
          (const __attribute__((address_space(1))) void*)ga,
          (__attribute__((address_space(3))) void*)(As + i * 512), 16, 0, 0);
      const unsigned short* gb = Wt + (size_t)(n0 + i * 8 + lr) * D + kk + lc * 8;
      __builtin_amdgcn_global_load_lds(
          (const __attribute__((address_space(1))) void*)gb,
          (__attribute__((address_space(3))) void*)(Bs + i * 512), 16, 0, 0);
    }
    __syncthreads();
#pragma unroll
    for (int kq = 0; kq < 2; kq++) {
      bf16x8 af[4], bfr[4];
#pragma unroll
      for (int mt = 0; mt < 4; mt++)
        af[mt] = *(const bf16x8*)(As + (mh * 64 + mt * 16 + c) * 64 + kq * 32 + q * 8);
#pragma unroll
      for (int nt = 0; nt < 4; nt++)
        bfr[nt] = *(const bf16x8*)(Bs + (nh * 64 + nt * 16 + c) * 64 + kq * 32 + q * 8);
#pragma unroll
      for (int mt = 0; mt < 4; mt++)
#pragma unroll
        for (int nt = 0; nt < 4; nt++)
          acc[mt][nt] = __builtin_amdgcn_mfma_f32_16x16x32_bf16(af[mt], bfr[nt], acc[mt][nt], 0, 0, 0);
    }
    __syncthreads();
  }

  int vcb[4]; float bv[4];
#pragma unroll
  for (int nt = 0; nt < 4; nt++) {
    vcb[nt] = n0 + nh * 64 + nt * 16 + c;
    bv[nt] = (vcb[nt] < V) ? bias[vcb[nt]] : 0.f;
  }
#pragma unroll
  for (int mt = 0; mt < 4; mt++) {
#pragma unroll
    for (int r = 0; r < 4; r++) {
      float x[4]; float m = NEG_INF;
#pragma unroll
      for (int nt = 0; nt < 4; nt++) {
        x[nt] = (vcb[nt] < V) ? (acc[mt][nt][r] + bv[nt]) : NEG_INF;
        m = fmaxf(m, x[nt]);
      }
#pragma unroll
      for (int o = 1; o < 16; o <<= 1) m = fmaxf(m, __shfl_xor(m, o));
      float s = 0.f;
#pragma unroll
      for (int nt = 0; nt < 4; nt++) s += __expf(x[nt] - m);
#pragma unroll
      for (int o = 1; o < 16; o <<= 1) s += __shfl_xor(s, o);
      if (c == 0) {
        int rloc = mh * 64 + mt * 16 + q * 4 + r;
        redM[nh][rloc] = m;
        redS[nh][rloc] = s;
      }
    }
  }
  __syncthreads();
  if (tid < 128) {
    float m0 = redM[0][tid], m1 = redM[1][tid];
    float mm = fmaxf(m0, m1);
    float ss = redS[0][tid] * __expf(m0 - mm) + redS[1][tid] * __expf(m1 - mm);
    partM[(size_t)cb * ROWS + row0 + tid] = mm;
    partS[(size_t)cb * ROWS + row0 + tid] = ss;
  }
}

// ---- combine 40 partials -> lse[row] ----
__global__ __launch_bounds__(256) void k_lse(const float* __restrict__ pM,
                                             const float* __restrict__ pS,
                                             float* __restrict__ lse) {
  int row = blockIdx.x * 256 + threadIdx.x;
  float m = pM[row], s = pS[row];
  for (int cb = 1; cb < NCB; cb++) {
    float M2 = pM[(size_t)cb * ROWS + row], S2 = pS[(size_t)cb * ROWS + row];
    float mn = fmaxf(m, M2);
    s = s * __expf(m - mn) + S2 * __expf(M2 - mn);
    m = mn;
  }
  lse[row] = m + __logf(s);
}

// ---- gathered logits at extended labels ----
__global__ __launch_bounds__(64) void k_gather(const unsigned short* __restrict__ A,
                                               const unsigned short* __restrict__ Wt,
                                               const float* __restrict__ bias,
                                               const int* __restrict__ labels,
                                               const float* __restrict__ lse,
                                               float* __restrict__ glog) {
  int lane = threadIdx.x, q = lane >> 4, c = lane & 15;
  int b = blockIdx.z, t0 = blockIdx.y * 16, s0 = blockIdx.x * 16;
  int s = s0 + c;
  int ev = (s < S && (s & 1)) ? labels[b * L + (s >> 1)] : 0;
  const unsigned short* Brow = Wt + (size_t)ev * D;
  const unsigned short* Arow = A + (size_t)(b * T + t0 + c) * D;
  f32x4 acc = {0.f, 0.f, 0.f, 0.f};
#pragma unroll
  for (int kk = 0; kk < D; kk += 32) {
    bf16x8 a = *(const bf16x8*)(Arow + kk + q * 8);
    bf16x8 bb = *(const bf16x8*)(Brow + kk + q * 8);
    acc = __builtin_amdgcn_mfma_f32_16x16x32_bf16(a, bb, acc, 0, 0, 0);
  }
  float bs = bias[ev];
#pragma unroll
  for (int r = 0; r < 4; r++) {
    int row = b * T + t0 + q * 4 + r;
    glog[(size_t)row * SP + s0 + c] = acc[r] + bs - lse[row];
  }
}

// ---- CTC forward DP: log domain, one wave per utterance, DPP neighbor,
//      straight-line 8-step chunks with register double-buffer prefetch ----
__global__ __launch_bounds__(64) void k_dp(const float* __restrict__ glog,
                                           const int* __restrict__ labels,
                                           const int* __restrict__ hlens,
                                           const int* __restrict__ llens,
                                           float* __restrict__ tot) {
  int b = blockIdx.x, l = threadIdx.x;
  // all lanes read safe clamped columns; lanes >=52 compute garbage that
  // never flows downward in s (transitions only go s-1/s-2 -> s)
  int col = 4 * l < SP ? 4 * l : SP - 4;
  const float* rp = glog + (size_t)(b * T) * SP + col;

  // skip gates: state 4l+1 skips from 4l-1 (prev-lane a3); 4l+3 skips from 4l+1
  int i0 = (2 * l < L) ? 2 * l : L - 1;
  int i1 = (2 * l + 1 < L) ? 2 * l + 1 : L - 1;
  int im = (l >= 1) ? 2 * l - 1 : 0; im = im < L ? im : L - 1;
  int lab0 = labels[b * L + i0];
  int lab1 = labels[b * L + i1];
  int labm = labels[b * L + im];
  bool sk1 = (l >= 1) && (lab0 != 0) && (lab0 != labm);
  bool sk3 = (lab1 != 0) && (lab1 != lab0);
  int hl = hlens[b];

  // init t=0
  float4 g0 = *(const float4*)rp;
  float a0 = (l == 0) ? g0.x : NEG_INF;
  float a1 = (l == 0) ? g0.y : NEG_INF;
  float a2 = NEG_INF, a3 = NEG_INF;

#define DP_STEP(G) {                                                          \
    float p3 = dpp_shr1_neginf(a3);              /* alpha[4l-1] */            \
    float s1 = sk1 ? p3 : NEG_INF;                                            \
    float m0 = fmaxf(a0, p3);                                                 \
    float n0 = m0 + __logf(__expf(a0 - m0) + __expf(p3 - m0)) + (G).x;        \
    float m1 = fmaxf(fmaxf(a1, a0), s1);                                      \
    float n1 = m1 + __logf(__expf(a1 - m1) + __expf(a0 - m1) + __expf(s1 - m1)) + (G).y; \
    float m2 = fmaxf(a2, a1);                                                 \
    float n2 = m2 + __logf(__expf(a2 - m2) + __expf(a1 - m2)) + (G).z;        \
    float s3 = sk3 ? a1 : NEG_INF;                                            \
    float m3 = fmaxf(fmaxf(a3, a2), s3);                                      \
    float n3 = m3 + __logf(__expf(a3 - m3) + __expf(a2 - m3) + __expf(s3 - m3)) + (G).w; \
    a0 = n0; a1 = n1; a2 = n2; a3 = n3; }

  int nsteps = hl - 1;           // steps t = 1 .. hl-1
  int full = nsteps >> 3;        // full 8-step chunks
  int rem = nsteps & 7;

  float4 cu[8], nx[8];
#pragma unroll
  for (int j = 0; j < 8; j++) cu[j] = *(const float4*)(rp + (size_t)(1 + j) * SP);

  for (int ch = 0; ch < full; ch++) {
    int tb = 1 + ch * 8;
#pragma unroll
    for (int j = 0; j < 8; j++) {
      int t = tb + 8 + j; t = t < T ? t : T - 1;     // safe clamp, value unused past hl
      nx[j] = *(const float4*)(rp + (size_t)t * SP);
    }
#pragma unroll
    for (int j = 0; j < 8; j++) DP_STEP(cu[j]);
#pragma unroll
    for (int j = 0; j < 8; j++) cu[j] = nx[j];
  }
#pragma unroll
  for (int j = 0; j < 7; j++) {
    if (j < rem) DP_STEP(cu[j]);
  }
#undef DP_STEP

  __shared__ float fin[256];
  fin[4 * l] = a0; fin[4 * l + 1] = a1; fin[4 * l + 2] = a2; fin[4 * l + 3] = a3;
  __syncthreads();
  if (l == 0) {
    int ll = llens[b];
    float aL = fin[2 * ll], aP = fin[2 * ll - 1];
    float m = fmaxf(aL, aP);
    tot[b] = m + __logf(__expf(aL - m) + __expf(aP - m));
  }
}

// ---- mean of -tot -> out[0] ----
__global__ void k_final(const float* __restrict__ tot, float* __restrict__ out) {
  int lane = threadIdx.x;
  float v = (lane < Bb) ? tot[lane] : 0.f;
#pragma unroll
  for (int o = 1; o < 16; o <<= 1) v += __shfl_xor(v, o);
  if (lane == 0) out[0] = -v / (float)Bb;
}

extern "C" void kernel_launch(void* const* d_in, const int* in_sizes, int n_in,
                              void* d_out, int out_size, void* d_ws, size_t ws_size,
                              hipStream_t stream) {
  const float* hs    = (const float*)d_in[0];
  const float* W     = (const float*)d_in[1];
  const float* bias  = (const float*)d_in[2];
  const int* hlens   = (const int*)d_in[3];
  const int* labels  = (const int*)d_in[4];
  const int* llens   = (const int*)d_in[5];
  float* out = (float*)d_out;

  char* ws = (char*)d_ws;
  unsigned short* A    = (unsigned short*)(ws);              // 12800*512*2 = 13,107,200
  unsigned short* Wt   = (unsigned short*)(ws + 13107200);   // 5120*512*2  =  5,242,880
  float*          partM= (float*)(ws + 18350080);            // 40*12800*4  =  2,048,000
  float*          partS= (float*)(ws + 20398080);            // 40*12800*4  =  2,048,000
  float*          lse  = (float*)(ws + 22446080);            // 12800*4     =     51,200
  float*          glog = (float*)(ws + 22497280);            // 12800*208*4 = 10,649,600
  float*          tot  = (float*)(ws + 33146880);            // 16*4

  k_conv_hs<<<ROWS * D / 1024, 256, 0, stream>>>(hs, A);
  k_transW<<<dim3(VP / 64, D / 64), 256, 0, stream>>>(W, Wt);
  k_gemm_lse<<<dim3(NCB, NRB), 256, 0, stream>>>(A, Wt, bias, partM, partS);
  k_lse<<<ROWS / 256, 256, 0, stream>>>(partM, partS, lse);
  k_gather<<<dim3(SP / 16, T / 16, Bb), 64, 0, stream>>>(A, Wt, bias, labels, lse, glog);
  k_dp<<<Bb, 64, 0, stream>>>(glog, labels, hlens, llens, tot);
  k_final<<<1, 64, 0, stream>>>(tot, out);

  (void)in_sizes; (void)n_in; (void)out_size; (void)ws_size;
}